// Round 1
// baseline (153.143 us; speedup 1.0000x reference)
//
#include <hip/hip_runtime.h>
#include <hip/hip_bf16.h>

typedef __bf16 bf16x8 __attribute__((ext_vector_type(8)));
typedef float f32x4 __attribute__((ext_vector_type(4)));

#define N_PIX 4608      // 2*48*48
#define D_MODEL 512
#define QKV_N 1536

// ---------------- conversion kernels ----------------

__global__ __launch_bounds__(256) void f32_to_bf16_kernel(
    const float* __restrict__ src, __bf16* __restrict__ dst, int n) {
  int i = (blockIdx.x * 256 + threadIdx.x) * 4;
  if (i + 3 < n) {
    float4 v = *(const float4*)&src[i];
    dst[i + 0] = (__bf16)v.x;
    dst[i + 1] = (__bf16)v.y;
    dst[i + 2] = (__bf16)v.z;
    dst[i + 3] = (__bf16)v.w;
  }
}

// dst[c][r] = (bf16) src[r][c]   src: R x C fp32, dst: C x R bf16
__global__ __launch_bounds__(256) void transpose_to_bf16_kernel(
    const float* __restrict__ src, __bf16* __restrict__ dst, int R, int C) {
  __shared__ float tile[32][33];
  int bx = blockIdx.x * 32;  // col base in src
  int by = blockIdx.y * 32;  // row base in src
  int tx = threadIdx.x;      // 0..31
  int ty = threadIdx.y;      // 0..7
#pragma unroll
  for (int i = 0; i < 32; i += 8)
    tile[ty + i][tx] = src[(by + ty + i) * C + bx + tx];
  __syncthreads();
#pragma unroll
  for (int i = 0; i < 32; i += 8)
    dst[(bx + ty + i) * R + by + tx] = (__bf16)tile[tx][ty + i];
}

// ---------------- bf16 MFMA GEMM ----------------
// C[M x N] = A[M x K] * Bt[N x K]^T ; 64x64 block tile, 4 waves, K-step 32.
// Verified gfx950 16x16x32 layouts (learn_hip m89):
//   A frag: A[m = lane&15][k = (lane>>4)*8 + j], j=0..7 contiguous
//   B frag: B[k = (lane>>4)*8 + j][n = lane&15]  == Bt[n][k] contiguous
//   C/D:    row = (lane>>4)*4 + reg, col = lane&15
__global__ __launch_bounds__(256) void gemm_bf16_kernel(
    const __bf16* __restrict__ A, const __bf16* __restrict__ Bt,
    void* __restrict__ C, int M, int N, int K, int c_is_f32) {
  __shared__ __bf16 sA[64][40];  // stride 40 bf16 = 80 B (16B-aligned, bank-uniform)
  __shared__ __bf16 sB[64][40];
  int tid = threadIdx.x;
  int wv = tid >> 6, lane = tid & 63;
  int m0 = blockIdx.y * 64, n0 = blockIdx.x * 64;
  int srow = tid >> 2;            // 0..63
  int skc = (tid & 3) * 8;        // 0,8,16,24
  int quad = lane >> 4, r16 = lane & 15;

  f32x4 acc[4] = {f32x4{0,0,0,0}, f32x4{0,0,0,0}, f32x4{0,0,0,0}, f32x4{0,0,0,0}};

  for (int k0 = 0; k0 < K; k0 += 32) {
    __syncthreads();
    *(uint4*)&sA[srow][skc] = *(const uint4*)&A[(m0 + srow) * K + k0 + skc];
    *(uint4*)&sB[srow][skc] = *(const uint4*)&Bt[(n0 + srow) * K + k0 + skc];
    __syncthreads();
    bf16x8 af = *(const bf16x8*)&sA[wv * 16 + r16][quad * 8];
#pragma unroll
    for (int t = 0; t < 4; ++t) {
      bf16x8 bfr = *(const bf16x8*)&sB[t * 16 + r16][quad * 8];
      acc[t] = __builtin_amdgcn_mfma_f32_16x16x32_bf16(af, bfr, acc[t], 0, 0, 0);
    }
  }

  __bf16* Cb = (__bf16*)C;
  float* Cf = (float*)C;
#pragma unroll
  for (int t = 0; t < 4; ++t) {
#pragma unroll
    for (int r = 0; r < 4; ++r) {
      int row = m0 + wv * 16 + quad * 4 + r;
      int col = n0 + t * 16 + r16;
      float v = acc[t][r];
      if (c_is_f32) Cf[row * N + col] = v;
      else          Cb[row * N + col] = (__bf16)v;
    }
  }
}

// ---------------- neighborhood attention ----------------
// qkv: [4608][1536] bf16, cols 0..511=Q(head,e), 512..1023=K, 1024..1535=V
// o:   [4608][512] bf16 in (n,h,w,head,e) layout
__global__ __launch_bounds__(256) void natten_attn_kernel(
    const __bf16* __restrict__ qkv, __bf16* __restrict__ o) {
  int tid = threadIdx.x;
  int wv = tid >> 6, lane = tid & 63;
  int g = blockIdx.x * 4 + wv;  // 0..36863
  int pix = g >> 3, head = g & 7;
  int n = pix / 2304;
  int rem = pix - n * 2304;
  int h = rem / 48;
  int w = rem - h * 48;
  int hs = h - 3; hs = hs < 0 ? 0 : (hs > 41 ? 41 : hs);
  int ws = w - 3; ws = ws < 0 ? 0 : (ws > 41 ? 41 : ws);

  __shared__ float sq[4][64];
  __shared__ float sp[4][64];

  const __bf16* qrow = qkv + pix * QKV_N + head * 64;
  sq[wv][lane] = (float)qrow[lane];
  __syncthreads();

  // phase 1: lane j < 49 computes logit for neighbor j = a*7+b
  float lg = -3.0e38f;
  {
    int a = lane / 7, b = lane - a * 7;
    if (lane < 49) {
      int pix2 = n * 2304 + (hs + a) * 48 + (ws + b);
      const bf16x8* kr = (const bf16x8*)(qkv + pix2 * QKV_N + 512 + head * 64);
      const float4* sq4 = (const float4*)sq[wv];
      float acc = 0.f;
#pragma unroll
      for (int c = 0; c < 8; ++c) {
        bf16x8 kk = kr[c];
        float4 q0 = sq4[2 * c], q1 = sq4[2 * c + 1];
        acc += q0.x * (float)kk[0] + q0.y * (float)kk[1] +
               q0.z * (float)kk[2] + q0.w * (float)kk[3] +
               q1.x * (float)kk[4] + q1.y * (float)kk[5] +
               q1.z * (float)kk[6] + q1.w * (float)kk[7];
      }
      lg = acc * 0.125f;  // q / sqrt(64)
    }
  }

  // softmax across lanes 0..48
  float mx = lg;
#pragma unroll
  for (int off = 32; off; off >>= 1) mx = fmaxf(mx, __shfl_xor(mx, off));
  float p = (lane < 49) ? __expf(lg - mx) : 0.f;
  float sm = p;
#pragma unroll
  for (int off = 32; off; off >>= 1) sm += __shfl_xor(sm, off);
  sp[wv][lane] = p / sm;
  __syncthreads();

  // phase 2: lane = e, coalesced accumulate over 49 neighbors
  float acc = 0.f;
#pragma unroll
  for (int a = 0; a < 7; ++a) {
#pragma unroll
    for (int b = 0; b < 7; ++b) {
      int pix2 = n * 2304 + (hs + a) * 48 + (ws + b);
      acc += sp[wv][a * 7 + b] * (float)qkv[pix2 * QKV_N + 1024 + head * 64 + lane];
    }
  }
  o[pix * D_MODEL + head * 64 + lane] = (__bf16)acc;
}

// ---------------- launch ----------------

extern "C" void kernel_launch(void* const* d_in, const int* in_sizes, int n_in,
                              void* d_out, int out_size, void* d_ws, size_t ws_size,
                              hipStream_t stream) {
  const float* x = (const float*)d_in[0];      // (2,48,48,512)
  const float* w_qkv = (const float*)d_in[1];  // (512,1536)
  const float* w_out = (const float*)d_in[2];  // (512,512)
  float* out = (float*)d_out;                  // (2,48,48,512)

  __bf16* ws = (__bf16*)d_ws;
  __bf16* xbf   = ws;                                   // 4608*512
  __bf16* wqkvT = xbf + N_PIX * D_MODEL;                // 1536*512
  __bf16* woutT = wqkvT + QKV_N * D_MODEL;              // 512*512
  __bf16* qkvb  = woutT + D_MODEL * D_MODEL;            // 4608*1536
  __bf16* obf   = qkvb + N_PIX * QKV_N;                 // 4608*512

  // 1. x -> bf16
  f32_to_bf16_kernel<<<N_PIX * D_MODEL / 1024, 256, 0, stream>>>(x, xbf, N_PIX * D_MODEL);
  // 2. w_qkv^T -> bf16 (1536 x 512)
  transpose_to_bf16_kernel<<<dim3(QKV_N / 32, D_MODEL / 32), dim3(32, 8), 0, stream>>>(
      w_qkv, wqkvT, D_MODEL, QKV_N);
  // 3. w_out^T -> bf16 (512 x 512)
  transpose_to_bf16_kernel<<<dim3(D_MODEL / 32, D_MODEL / 32), dim3(32, 8), 0, stream>>>(
      w_out, woutT, D_MODEL, D_MODEL);
  // 4. qkv = xbf @ w_qkv  -> bf16 (4608 x 1536)
  gemm_bf16_kernel<<<dim3(QKV_N / 64, N_PIX / 64), 256, 0, stream>>>(
      xbf, wqkvT, qkvb, N_PIX, QKV_N, D_MODEL, 0);
  // 5. attention -> obf (4608 x 512)
  natten_attn_kernel<<<N_PIX * 8 / 4, 256, 0, stream>>>(qkvb, obf);
  // 6. out = obf @ w_out -> fp32 d_out
  gemm_bf16_kernel<<<dim3(D_MODEL / 64, N_PIX / 64), 256, 0, stream>>>(
      obf, woutT, out, N_PIX, D_MODEL, D_MODEL, 1);
}

// Round 2
// 131.101 us; speedup vs baseline: 1.1681x; 1.1681x over previous
//
#include <hip/hip_runtime.h>
#include <hip/hip_bf16.h>

typedef __bf16 bf16x8 __attribute__((ext_vector_type(8)));
typedef float f32x4 __attribute__((ext_vector_type(4)));

#define N_PIX 4608      // 2*48*48
#define D_MODEL 512
#define QKV_N 1536

// async global->LDS, 16B per lane. LDS dest must be wave-uniform base; HW adds lane*16.
__device__ __forceinline__ void gload_lds16(const void* g, void* l) {
  __builtin_amdgcn_global_load_lds(
      (const __attribute__((address_space(1))) unsigned int*)g,
      (__attribute__((address_space(3))) unsigned int*)l, 16, 0, 0);
}

// ---------------- conversion kernels ----------------

__global__ __launch_bounds__(256) void f32_to_bf16_kernel(
    const float* __restrict__ src, __bf16* __restrict__ dst, int n) {
  int i = (blockIdx.x * 256 + threadIdx.x) * 4;
  if (i + 3 < n) {
    float4 v = *(const float4*)&src[i];
    dst[i + 0] = (__bf16)v.x;
    dst[i + 1] = (__bf16)v.y;
    dst[i + 2] = (__bf16)v.z;
    dst[i + 3] = (__bf16)v.w;
  }
}

// dst[c][r] = (bf16) src[r][c]   src: R x C fp32, dst: C x R bf16
__global__ __launch_bounds__(256) void transpose_to_bf16_kernel(
    const float* __restrict__ src, __bf16* __restrict__ dst, int R, int C) {
  __shared__ float tile[32][33];
  int bx = blockIdx.x * 32;
  int by = blockIdx.y * 32;
  int tx = threadIdx.x;
  int ty = threadIdx.y;
#pragma unroll
  for (int i = 0; i < 32; i += 8)
    tile[ty + i][tx] = src[(by + ty + i) * C + bx + tx];
  __syncthreads();
#pragma unroll
  for (int i = 0; i < 32; i += 8)
    dst[(bx + ty + i) * R + by + tx] = (__bf16)tile[tx][ty + i];
}

// ---------------- bf16 MFMA GEMM, m97 structure ----------------
// C[MxN] = A[MxK] * Bt[NxK]^T. 128x128 tile, BK=32, 4 waves, each wave 64x64 out.
// Staging via global_load_lds width=16: LDS layout [row][32k] contiguous (no pad).
// Fragment layouts (verified m89): A[m=lane&15][k=quad*8+j]; Bt[n=lane&15][k=quad*8+j];
// C/D: row=quad*4+reg, col=lane&15.
__global__ __launch_bounds__(256) void gemm128_kernel(
    const __bf16* __restrict__ A, const __bf16* __restrict__ Bt,
    void* __restrict__ C, int M, int N, int K, int c_is_f32) {
  __shared__ __bf16 sA[128 * 32];
  __shared__ __bf16 sB[128 * 32];
  int tid = threadIdx.x;
  int wv = tid >> 6, lane = tid & 63;
  int quad = lane >> 4, r16 = lane & 15;
  int m0 = blockIdx.y * 128, n0 = blockIdx.x * 128;

  // staging: wave wv fills rows [wv*32, wv*32+32) of both tiles via 2 instrs each
  int rA = lane >> 2;          // 0..15
  int kc = (lane & 3) * 8;     // 0,8,16,24
  const __bf16* Ag0 = A + (long)(m0 + wv * 32 + rA) * K + kc;
  const __bf16* Ag1 = Ag0 + (long)16 * K;
  const __bf16* Bg0 = Bt + (long)(n0 + wv * 32 + rA) * K + kc;
  const __bf16* Bg1 = Bg0 + (long)16 * K;
  __bf16* sA0 = &sA[(wv * 32) * 32];
  __bf16* sA1 = &sA[(wv * 32 + 16) * 32];
  __bf16* sB0 = &sB[(wv * 32) * 32];
  __bf16* sB1 = &sB[(wv * 32 + 16) * 32];

  int mw = (wv & 1) * 64, nw = (wv >> 1) * 64;

  f32x4 acc[4][4];
#pragma unroll
  for (int mt = 0; mt < 4; ++mt)
#pragma unroll
    for (int nt = 0; nt < 4; ++nt) acc[mt][nt] = f32x4{0.f, 0.f, 0.f, 0.f};

  for (int k0 = 0; k0 < K; k0 += 32) {
    __syncthreads();
    gload_lds16(Ag0 + k0, sA0);
    gload_lds16(Ag1 + k0, sA1);
    gload_lds16(Bg0 + k0, sB0);
    gload_lds16(Bg1 + k0, sB1);
    __syncthreads();
    bf16x8 af[4], bfr[4];
#pragma unroll
    for (int mt = 0; mt < 4; ++mt)
      af[mt] = *(const bf16x8*)&sA[(mw + mt * 16 + r16) * 32 + quad * 8];
#pragma unroll
    for (int nt = 0; nt < 4; ++nt)
      bfr[nt] = *(const bf16x8*)&sB[(nw + nt * 16 + r16) * 32 + quad * 8];
#pragma unroll
    for (int mt = 0; mt < 4; ++mt)
#pragma unroll
      for (int nt = 0; nt < 4; ++nt)
        acc[mt][nt] = __builtin_amdgcn_mfma_f32_16x16x32_bf16(af[mt], bfr[nt], acc[mt][nt], 0, 0, 0);
  }

  __bf16* Cb = (__bf16*)C;
  float* Cf = (float*)C;
#pragma unroll
  for (int mt = 0; mt < 4; ++mt)
#pragma unroll
    for (int r = 0; r < 4; ++r) {
      int row = m0 + mw + mt * 16 + quad * 4 + r;
#pragma unroll
      for (int nt = 0; nt < 4; ++nt) {
        int col = n0 + nw + nt * 16 + r16;
        float v = acc[mt][nt][r];
        if (c_is_f32) Cf[(long)row * N + col] = v;
        else          Cb[(long)row * N + col] = (__bf16)v;
      }
    }
}

// ---------------- neighborhood attention, LDS-tiled ----------------
// Block = 8x8 query tile x 1 head. Stage 14x14 K/V halo (64ch bf16) in LDS.
// 4 lanes per query, each owns 16 channels. Row stride 72 elems (144 B: 16B-aligned,
// +4-bank shift per row for conflict spread).
#define KSTR 72
__global__ __launch_bounds__(256) void natten_attn_kernel(
    const __bf16* __restrict__ qkv, __bf16* __restrict__ o) {
  __shared__ __bf16 sK[196 * KSTR];
  __shared__ __bf16 sV[196 * KSTR];
  int tid = threadIdx.x;
  int bid = blockIdx.x;                 // 0..575
  int nB = bid / 288;
  int rem = bid - nB * 288;
  int head = rem / 36;
  int tile = rem - head * 36;
  int tr = tile / 6, tc = tile - tr * 6;
  int r0 = tr * 8, c0 = tc * 8;
  int loH = r0 - 3; loH = loH < 0 ? 0 : (loH > 41 ? 41 : loH);
  int loW = c0 - 3; loW = loW < 0 ? 0 : (loW > 41 ? 41 : loW);

  // stage K/V: 196 rows x 128 B each
  for (int j = tid; j < 196 * 8; j += 256) {
    int rowi = j >> 3, ch = j & 7;
    int rr = rowi / 14, cc = rowi - rr * 14;
    int hh = loH + rr; hh = hh > 47 ? 47 : hh;
    int wp = loW + cc; wp = wp > 47 ? 47 : wp;
    long base = (long)(nB * 2304 + hh * 48 + wp) * QKV_N + head * 64 + ch * 8;
    *(uint4*)&sK[rowi * KSTR + ch * 8] = *(const uint4*)&qkv[base + 512];
    *(uint4*)&sV[rowi * KSTR + ch * 8] = *(const uint4*)&qkv[base + 1024];
  }
  __syncthreads();

  int q = tid >> 2, s = tid & 3;
  int qr = q >> 3, qc = q & 7;
  int h = r0 + qr, w = c0 + qc;
  int pix = nB * 2304 + h * 48 + w;
  int hs = h - 3; hs = hs < 0 ? 0 : (hs > 41 ? 41 : hs); hs -= loH;
  int ws = w - 3; ws = ws < 0 ? 0 : (ws > 41 ? 41 : ws); ws -= loW;
  int base = (hs * 14 + ws) * KSTR + s * 16;

  // q fragment: 16 channels, scale folded
  const bf16x8* qp = (const bf16x8*)&qkv[(long)pix * QKV_N + head * 64 + s * 16];
  bf16x8 q0 = qp[0], q1 = qp[1];
  float qf[16];
#pragma unroll
  for (int t = 0; t < 8; ++t) {
    qf[t] = (float)q0[t] * 0.125f;
    qf[8 + t] = (float)q1[t] * 0.125f;
  }

  // phase 1: 49 logits (16-ch partial + 4-lane shuffle reduce)
  float lg[49];
#pragma unroll
  for (int j = 0; j < 49; ++j) {
    int a = j / 7, b = j % 7;
    const bf16x8* kp = (const bf16x8*)&sK[base + (a * 14 + b) * KSTR];
    bf16x8 k0 = kp[0], k1 = kp[1];
    float acc = 0.f;
#pragma unroll
    for (int t = 0; t < 8; ++t) {
      acc = fmaf(qf[t], (float)k0[t], acc);
      acc = fmaf(qf[8 + t], (float)k1[t], acc);
    }
    acc += __shfl_xor(acc, 1);
    acc += __shfl_xor(acc, 2);
    lg[j] = acc;
  }

  // softmax (replicated across the 4 lanes of a query — free)
  float mx = lg[0];
#pragma unroll
  for (int j = 1; j < 49; ++j) mx = fmaxf(mx, lg[j]);
  float sm = 0.f;
#pragma unroll
  for (int j = 0; j < 49; ++j) { lg[j] = __expf(lg[j] - mx); sm += lg[j]; }
  float inv = 1.f / sm;

  // phase 2: PV
  float ov[16];
#pragma unroll
  for (int t = 0; t < 16; ++t) ov[t] = 0.f;
#pragma unroll
  for (int j = 0; j < 49; ++j) {
    int a = j / 7, b = j % 7;
    float pj = lg[j] * inv;
    const bf16x8* vp = (const bf16x8*)&sV[base + (a * 14 + b) * KSTR];
    bf16x8 v0 = vp[0], v1 = vp[1];
#pragma unroll
    for (int t = 0; t < 8; ++t) {
      ov[t] = fmaf(pj, (float)v0[t], ov[t]);
      ov[8 + t] = fmaf(pj, (float)v1[t], ov[8 + t]);
    }
  }

  bf16x8 o0, o1;
#pragma unroll
  for (int t = 0; t < 8; ++t) {
    o0[t] = (__bf16)ov[t];
    o1[t] = (__bf16)ov[8 + t];
  }
  bf16x8* op = (bf16x8*)&o[(long)pix * D_MODEL + head * 64 + s * 16];
  op[0] = o0;
  op[1] = o1;
}

// ---------------- launch ----------------

extern "C" void kernel_launch(void* const* d_in, const int* in_sizes, int n_in,
                              void* d_out, int out_size, void* d_ws, size_t ws_size,
                              hipStream_t stream) {
  const float* x = (const float*)d_in[0];      // (2,48,48,512)
  const float* w_qkv = (const float*)d_in[1];  // (512,1536)
  const float* w_out = (const float*)d_in[2];  // (512,512)
  float* out = (float*)d_out;                  // (2,48,48,512)

  __bf16* ws = (__bf16*)d_ws;
  __bf16* xbf   = ws;                                   // 4608*512
  __bf16* wqkvT = xbf + N_PIX * D_MODEL;                // 1536*512
  __bf16* woutT = wqkvT + QKV_N * D_MODEL;              // 512*512
  __bf16* qkvb  = woutT + D_MODEL * D_MODEL;            // 4608*1536
  __bf16* obf   = qkvb + N_PIX * QKV_N;                 // 4608*512

  f32_to_bf16_kernel<<<N_PIX * D_MODEL / 1024, 256, 0, stream>>>(x, xbf, N_PIX * D_MODEL);
  transpose_to_bf16_kernel<<<dim3(QKV_N / 32, D_MODEL / 32), dim3(32, 8), 0, stream>>>(
      w_qkv, wqkvT, D_MODEL, QKV_N);
  transpose_to_bf16_kernel<<<dim3(D_MODEL / 32, D_MODEL / 32), dim3(32, 8), 0, stream>>>(
      w_out, woutT, D_MODEL, D_MODEL);
  // qkv = xbf @ w_qkv -> bf16 (4608 x 1536)
  gemm128_kernel<<<dim3(QKV_N / 128, N_PIX / 128), 256, 0, stream>>>(
      xbf, wqkvT, qkvb, N_PIX, QKV_N, D_MODEL, 0);
  // attention -> obf (4608 x 512)
  natten_attn_kernel<<<576, 256, 0, stream>>>(qkvb, obf);
  // out = obf @ w_out -> fp32
  gemm128_kernel<<<dim3(D_MODEL / 128, N_PIX / 128), 256, 0, stream>>>(
      obf, woutT, out, N_PIX, D_MODEL, D_MODEL, 1);
}

// Round 3
// 124.329 us; speedup vs baseline: 1.2318x; 1.0545x over previous
//
#include <hip/hip_runtime.h>
#include <hip/hip_bf16.h>

typedef __bf16 bf16x4 __attribute__((ext_vector_type(4)));
typedef __bf16 bf16x8 __attribute__((ext_vector_type(8)));
typedef float f32x4 __attribute__((ext_vector_type(4)));

#define N_PIX 4608      // 2*48*48
#define D_MODEL 512
#define QKV_N 1536

// async global->LDS, 16B per lane. LDS dest is wave-uniform base; HW adds lane*16.
__device__ __forceinline__ void gload_lds16(const void* g, void* l) {
  __builtin_amdgcn_global_load_lds(
      (const __attribute__((address_space(1))) unsigned int*)g,
      (__attribute__((address_space(3))) unsigned int*)l, 16, 0, 0);
}

// ---------------- fused prep: x->bf16 + both weight transposes ----------------
// blocks [0,2304): x convert; [2304,3072): w_qkv^T; [3072,3328): w_out^T
__global__ __launch_bounds__(256) void prep_kernel(
    const float* __restrict__ x, const float* __restrict__ wq,
    const float* __restrict__ wo, __bf16* __restrict__ xbf,
    __bf16* __restrict__ wqT, __bf16* __restrict__ woT) {
  int b = blockIdx.x, tid = threadIdx.x;
  if (b < 2304) {
    int i = b * 1024 + tid * 4;
    float4 v = *(const float4*)&x[i];
    bf16x4 o = {(__bf16)v.x, (__bf16)v.y, (__bf16)v.z, (__bf16)v.w};
    *(bf16x4*)&xbf[i] = o;
    return;
  }
  __shared__ float tile[32][33];
  const float* src; __bf16* dst; int R, C, bx, by;
  if (b < 3072) {
    int t = b - 2304; src = wq; dst = wqT; R = 512; C = 1536;
    bx = (t % 48) * 32; by = (t / 48) * 32;
  } else {
    int t = b - 3072; src = wo; dst = woT; R = 512; C = 512;
    bx = (t & 15) * 32; by = (t >> 4) * 32;
  }
  int tx = tid & 31, ty = tid >> 5;
#pragma unroll
  for (int i = 0; i < 32; i += 8)
    tile[ty + i][tx] = src[(by + ty + i) * C + bx + tx];
  __syncthreads();
#pragma unroll
  for (int i = 0; i < 32; i += 8)
    dst[(bx + ty + i) * R + by + tx] = (__bf16)tile[tx][ty + i];
}

// ---------------- bf16 MFMA GEMM, double-buffered global_load_lds ----------------
// C[MxN] = A[MxK] * Bt[NxK]^T. Block tile 128 x BN, BK=32, 4 waves (2x2), wave
// tile 64 x BN/2. One barrier per K-iter; prefetch for iter k+1 in flight during
// iter k's MFMA (drained by the compiler's vmcnt(0)-before-s_barrier).
// Fragment layouts (verified m89): A[m=lane&15][k=quad*8+j]; Bt[n=lane&15][k=quad*8+j];
// C/D: row=quad*4+reg, col=lane&15.
template <int BN>
__global__ __launch_bounds__(256) void gemm128_kernel(
    const __bf16* __restrict__ A, const __bf16* __restrict__ Bt,
    void* __restrict__ C, int M, int N, int K, int c_is_f32) {
  constexpr int NT = BN / 32;      // MFMA col-tiles per wave
  constexpr int BROWS = BN / 4;    // B rows staged per wave (32 or 16)
  __shared__ __bf16 sA[2][128 * 32];
  __shared__ __bf16 sB[2][BN * 32];
  int tid = threadIdx.x;
  int wv = tid >> 6, lane = tid & 63;
  int quad = lane >> 4, r16 = lane & 15;
  int m0 = blockIdx.y * 128, n0 = blockIdx.x * BN;

  int rA = lane >> 2;           // 0..15
  int kc = (lane & 3) * 8;      // 0,8,16,24
  const __bf16* Ag0 = A + (long)(m0 + wv * 32 + rA) * K + kc;
  const __bf16* Ag1 = Ag0 + (long)16 * K;
  const __bf16* Bg0 = Bt + (long)(n0 + wv * BROWS + rA) * K + kc;

  int mw = (wv & 1) * 64, nw = (wv >> 1) * (BN / 2);

  f32x4 acc[4][NT];
#pragma unroll
  for (int mt = 0; mt < 4; ++mt)
#pragma unroll
    for (int nt = 0; nt < NT; ++nt) acc[mt][nt] = f32x4{0.f, 0.f, 0.f, 0.f};

  auto stage = [&](int buf, int k0) {
    gload_lds16(Ag0 + k0, &sA[buf][(wv * 32) * 32]);
    gload_lds16(Ag1 + k0, &sA[buf][(wv * 32 + 16) * 32]);
    gload_lds16(Bg0 + k0, &sB[buf][(wv * BROWS) * 32]);
    if (BROWS == 32)
      gload_lds16(Bg0 + (long)16 * K + k0, &sB[buf][(wv * BROWS + 16) * 32]);
  };

  stage(0, 0);
  int cur = 0;
  for (int k0 = 0; k0 < K; k0 += 32) {
    __syncthreads();                       // drains cur's loads (vmcnt0 + barrier)
    if (k0 + 32 < K) stage(cur ^ 1, k0 + 32);  // in flight during MFMA below
    bf16x8 af[4], bfr[NT];
#pragma unroll
    for (int mt = 0; mt < 4; ++mt)
      af[mt] = *(const bf16x8*)&sA[cur][(mw + mt * 16 + r16) * 32 + quad * 8];
#pragma unroll
    for (int nt = 0; nt < NT; ++nt)
      bfr[nt] = *(const bf16x8*)&sB[cur][(nw + nt * 16 + r16) * 32 + quad * 8];
#pragma unroll
    for (int mt = 0; mt < 4; ++mt)
#pragma unroll
      for (int nt = 0; nt < NT; ++nt)
        acc[mt][nt] = __builtin_amdgcn_mfma_f32_16x16x32_bf16(af[mt], bfr[nt], acc[mt][nt], 0, 0, 0);
    cur ^= 1;
  }

  __bf16* Cb = (__bf16*)C;
  float* Cf = (float*)C;
#pragma unroll
  for (int mt = 0; mt < 4; ++mt)
#pragma unroll
    for (int r = 0; r < 4; ++r) {
      int row = m0 + mw + mt * 16 + quad * 4 + r;
#pragma unroll
      for (int nt = 0; nt < NT; ++nt) {
        int col = n0 + nw + nt * 16 + r16;
        float v = acc[mt][nt][r];
        if (c_is_f32) Cf[(long)row * N + col] = v;
        else          Cb[(long)row * N + col] = (__bf16)v;
      }
    }
}

// ---------------- neighborhood attention, LDS-tiled ----------------
// Block = 8x8 query tile x 1 head. Stage 14x14 K/V halo (64ch bf16) in LDS.
// 4 lanes per query, each owns 16 channels. Row stride 72 elems (144 B).
#define KSTR 72
__global__ __launch_bounds__(256) void natten_attn_kernel(
    const __bf16* __restrict__ qkv, __bf16* __restrict__ o) {
  __shared__ __bf16 sK[196 * KSTR];
  __shared__ __bf16 sV[196 * KSTR];
  int tid = threadIdx.x;
  int bid = blockIdx.x;                 // 0..575
  int nB = bid / 288;
  int rem = bid - nB * 288;
  int head = rem / 36;
  int tile = rem - head * 36;
  int tr = tile / 6, tc = tile - tr * 6;
  int r0 = tr * 8, c0 = tc * 8;
  int loH = r0 - 3; loH = loH < 0 ? 0 : (loH > 41 ? 41 : loH);
  int loW = c0 - 3; loW = loW < 0 ? 0 : (loW > 41 ? 41 : loW);

  for (int j = tid; j < 196 * 8; j += 256) {
    int rowi = j >> 3, ch = j & 7;
    int rr = rowi / 14, cc = rowi - rr * 14;
    int hh = loH + rr; hh = hh > 47 ? 47 : hh;
    int wp = loW + cc; wp = wp > 47 ? 47 : wp;
    long base = (long)(nB * 2304 + hh * 48 + wp) * QKV_N + head * 64 + ch * 8;
    *(uint4*)&sK[rowi * KSTR + ch * 8] = *(const uint4*)&qkv[base + 512];
    *(uint4*)&sV[rowi * KSTR + ch * 8] = *(const uint4*)&qkv[base + 1024];
  }
  __syncthreads();

  int q = tid >> 2, s = tid & 3;
  int qr = q >> 3, qc = q & 7;
  int h = r0 + qr, w = c0 + qc;
  int pix = nB * 2304 + h * 48 + w;
  int hs = h - 3; hs = hs < 0 ? 0 : (hs > 41 ? 41 : hs); hs -= loH;
  int ws = w - 3; ws = ws < 0 ? 0 : (ws > 41 ? 41 : ws); ws -= loW;
  int base = (hs * 14 + ws) * KSTR + s * 16;

  const bf16x8* qp = (const bf16x8*)&qkv[(long)pix * QKV_N + head * 64 + s * 16];
  bf16x8 q0 = qp[0], q1 = qp[1];
  float qf[16];
#pragma unroll
  for (int t = 0; t < 8; ++t) {
    qf[t] = (float)q0[t] * 0.125f;
    qf[8 + t] = (float)q1[t] * 0.125f;
  }

  float lg[49];
#pragma unroll
  for (int j = 0; j < 49; ++j) {
    int a = j / 7, b = j % 7;
    const bf16x8* kp = (const bf16x8*)&sK[base + (a * 14 + b) * KSTR];
    bf16x8 k0 = kp[0], k1 = kp[1];
    float acc = 0.f;
#pragma unroll
    for (int t = 0; t < 8; ++t) {
      acc = fmaf(qf[t], (float)k0[t], acc);
      acc = fmaf(qf[8 + t], (float)k1[t], acc);
    }
    acc += __shfl_xor(acc, 1);
    acc += __shfl_xor(acc, 2);
    lg[j] = acc;
  }

  float mx = lg[0];
#pragma unroll
  for (int j = 1; j < 49; ++j) mx = fmaxf(mx, lg[j]);
  float sm = 0.f;
#pragma unroll
  for (int j = 0; j < 49; ++j) { lg[j] = __expf(lg[j] - mx); sm += lg[j]; }
  float inv = 1.f / sm;

  float ov[16];
#pragma unroll
  for (int t = 0; t < 16; ++t) ov[t] = 0.f;
#pragma unroll
  for (int j = 0; j < 49; ++j) {
    int a = j / 7, b = j % 7;
    float pj = lg[j] * inv;
    const bf16x8* vp = (const bf16x8*)&sV[base + (a * 14 + b) * KSTR];
    bf16x8 v0 = vp[0], v1 = vp[1];
#pragma unroll
    for (int t = 0; t < 8; ++t) {
      ov[t] = fmaf(pj, (float)v0[t], ov[t]);
      ov[8 + t] = fmaf(pj, (float)v1[t], ov[8 + t]);
    }
  }

  bf16x8 o0, o1;
#pragma unroll
  for (int t = 0; t < 8; ++t) {
    o0[t] = (__bf16)ov[t];
    o1[t] = (__bf16)ov[8 + t];
  }
  bf16x8* op = (bf16x8*)&o[(long)pix * D_MODEL + head * 64 + s * 16];
  op[0] = o0;
  op[1] = o1;
}

// ---------------- launch ----------------

extern "C" void kernel_launch(void* const* d_in, const int* in_sizes, int n_in,
                              void* d_out, int out_size, void* d_ws, size_t ws_size,
                              hipStream_t stream) {
  const float* x = (const float*)d_in[0];      // (2,48,48,512)
  const float* w_qkv = (const float*)d_in[1];  // (512,1536)
  const float* w_out = (const float*)d_in[2];  // (512,512)
  float* out = (float*)d_out;                  // (2,48,48,512)

  __bf16* ws = (__bf16*)d_ws;
  __bf16* xbf   = ws;                                   // 4608*512
  __bf16* wqkvT = xbf + N_PIX * D_MODEL;                // 1536*512
  __bf16* woutT = wqkvT + QKV_N * D_MODEL;              // 512*512
  __bf16* qkvb  = woutT + D_MODEL * D_MODEL;            // 4608*1536
  __bf16* obf   = qkvb + N_PIX * QKV_N;                 // 4608*512

  // prep: x->bf16 (2304 blocks) + w_qkv^T (768) + w_out^T (256)
  prep_kernel<<<3328, 256, 0, stream>>>(x, w_qkv, w_out, xbf, wqkvT, woutT);
  // qkv = xbf @ w_qkv -> bf16 (4608 x 1536), 12x36 = 432 blocks
  gemm128_kernel<128><<<dim3(QKV_N / 128, N_PIX / 128), 256, 0, stream>>>(
      xbf, wqkvT, qkvb, N_PIX, QKV_N, D_MODEL, 0);
  // attention -> obf (4608 x 512)
  natten_attn_kernel<<<576, 256, 0, stream>>>(qkvb, obf);
  // out = obf @ w_out -> fp32, 8x36 = 288 blocks (BN=64 for occupancy)
  gemm128_kernel<64><<<dim3(D_MODEL / 64, N_PIX / 128), 256, 0, stream>>>(
      obf, woutT, out, N_PIX, D_MODEL, D_MODEL, 1);
}

// Round 4
// 124.318 us; speedup vs baseline: 1.2319x; 1.0001x over previous
//
#include <hip/hip_runtime.h>
#include <hip/hip_bf16.h>

typedef __bf16 bf16x4 __attribute__((ext_vector_type(4)));
typedef __bf16 bf16x8 __attribute__((ext_vector_type(8)));
typedef float f32x4 __attribute__((ext_vector_type(4)));

#define N_PIX 4608      // 2*48*48
#define D_MODEL 512
#define QKV_N 1536

// async global->LDS, 16B per lane. LDS dest is wave-uniform base; HW adds lane*16.
__device__ __forceinline__ void gload_lds16(const void* g, void* l) {
  __builtin_amdgcn_global_load_lds(
      (const __attribute__((address_space(1))) unsigned int*)g,
      (__attribute__((address_space(3))) unsigned int*)l, 16, 0, 0);
}

// ---------------- fused prep: x->bf16 + both weight transposes ----------------
// blocks [0,2304): x convert; [2304,3072): w_qkv^T (q-scale folded); [3072,3328): w_out^T
__global__ __launch_bounds__(256) void prep_kernel(
    const float* __restrict__ x, const float* __restrict__ wq,
    const float* __restrict__ wo, __bf16* __restrict__ xbf,
    __bf16* __restrict__ wqT, __bf16* __restrict__ woT) {
  int b = blockIdx.x, tid = threadIdx.x;
  if (b < 2304) {
    int i = b * 1024 + tid * 4;
    float4 v = *(const float4*)&x[i];
    bf16x4 o = {(__bf16)v.x, (__bf16)v.y, (__bf16)v.z, (__bf16)v.w};
    *(bf16x4*)&xbf[i] = o;
    return;
  }
  __shared__ float tile[32][33];
  const float* src; __bf16* dst; int R, C, bx, by;
  bool is_wq;
  if (b < 3072) {
    int t = b - 2304; src = wq; dst = wqT; R = 512; C = 1536;
    bx = (t % 48) * 32; by = (t / 48) * 32; is_wq = true;
  } else {
    int t = b - 3072; src = wo; dst = woT; R = 512; C = 512;
    bx = (t & 15) * 32; by = (t >> 4) * 32; is_wq = false;
  }
  int tx = tid & 31, ty = tid >> 5;
#pragma unroll
  for (int i = 0; i < 32; i += 8)
    tile[ty + i][tx] = src[(by + ty + i) * C + bx + tx];
  __syncthreads();
#pragma unroll
  for (int i = 0; i < 32; i += 8) {
    int outrow = bx + ty + i;
    float v = tile[tx][ty + i];
    if (is_wq && outrow < 512) v *= 0.125f;  // fold q/sqrt(D_HEAD) into weights
    dst[outrow * R + by + tx] = (__bf16)v;
  }
}

// ---------------- bf16 MFMA GEMM, double-buffered global_load_lds ----------------
// C[MxN] = A[MxK] * Bt[NxK]^T. Block tile 128 x BN, BK=32, 4 waves (2x2), wave
// tile 64 x BN/2. One barrier per K-iter; prefetch for iter k+1 in flight during
// iter k's MFMA.
// Fragment layouts (verified m89): A[m=lane&15][k=quad*8+j]; Bt[n=lane&15][k=quad*8+j];
// C/D: row=quad*4+reg, col=lane&15.
template <int BN>
__global__ __launch_bounds__(256) void gemm128_kernel(
    const __bf16* __restrict__ A, const __bf16* __restrict__ Bt,
    void* __restrict__ C, int M, int N, int K, int c_is_f32) {
  constexpr int NT = BN / 32;      // MFMA col-tiles per wave
  constexpr int BROWS = BN / 4;    // B rows staged per wave (32 or 16)
  __shared__ __bf16 sA[2][128 * 32];
  __shared__ __bf16 sB[2][BN * 32];
  int tid = threadIdx.x;
  int wv = tid >> 6, lane = tid & 63;
  int quad = lane >> 4, r16 = lane & 15;
  int m0 = blockIdx.y * 128, n0 = blockIdx.x * BN;

  int rA = lane >> 2;           // 0..15
  int kc = (lane & 3) * 8;      // 0,8,16,24
  const __bf16* Ag0 = A + (long)(m0 + wv * 32 + rA) * K + kc;
  const __bf16* Ag1 = Ag0 + (long)16 * K;
  const __bf16* Bg0 = Bt + (long)(n0 + wv * BROWS + rA) * K + kc;

  int mw = (wv & 1) * 64, nw = (wv >> 1) * (BN / 2);

  f32x4 acc[4][NT];
#pragma unroll
  for (int mt = 0; mt < 4; ++mt)
#pragma unroll
    for (int nt = 0; nt < NT; ++nt) acc[mt][nt] = f32x4{0.f, 0.f, 0.f, 0.f};

  auto stage = [&](int buf, int k0) {
    gload_lds16(Ag0 + k0, &sA[buf][(wv * 32) * 32]);
    gload_lds16(Ag1 + k0, &sA[buf][(wv * 32 + 16) * 32]);
    gload_lds16(Bg0 + k0, &sB[buf][(wv * BROWS) * 32]);
    if (BROWS == 32)
      gload_lds16(Bg0 + (long)16 * K + k0, &sB[buf][(wv * BROWS + 16) * 32]);
  };

  stage(0, 0);
  int cur = 0;
  for (int k0 = 0; k0 < K; k0 += 32) {
    __syncthreads();
    if (k0 + 32 < K) stage(cur ^ 1, k0 + 32);
    bf16x8 af[4], bfr[NT];
#pragma unroll
    for (int mt = 0; mt < 4; ++mt)
      af[mt] = *(const bf16x8*)&sA[cur][(mw + mt * 16 + r16) * 32 + quad * 8];
#pragma unroll
    for (int nt = 0; nt < NT; ++nt)
      bfr[nt] = *(const bf16x8*)&sB[cur][(nw + nt * 16 + r16) * 32 + quad * 8];
#pragma unroll
    for (int mt = 0; mt < 4; ++mt)
#pragma unroll
      for (int nt = 0; nt < NT; ++nt)
        acc[mt][nt] = __builtin_amdgcn_mfma_f32_16x16x32_bf16(af[mt], bfr[nt], acc[mt][nt], 0, 0, 0);
    cur ^= 1;
  }

  __bf16* Cb = (__bf16*)C;
  float* Cf = (float*)C;
#pragma unroll
  for (int mt = 0; mt < 4; ++mt)
#pragma unroll
    for (int r = 0; r < 4; ++r) {
      int row = m0 + mw + mt * 16 + quad * 4 + r;
#pragma unroll
      for (int nt = 0; nt < NT; ++nt) {
        int col = n0 + nw + nt * 16 + r16;
        float v = acc[mt][nt][r];
        if (c_is_f32) Cf[(long)row * N + col] = v;
        else          Cb[(long)row * N + col] = (__bf16)v;
      }
    }
}

// ---------------- neighborhood attention, LDS-tiled, 512 threads ----------------
// Block = 8x8 query tile x 1 head, 8 waves. Stage 14x14 K/V halo (64ch bf16) in LDS.
// 8 lanes per query, each owns 8 channels. Row stride 72 elems (144 B).
// q-scale is pre-folded into w_qkv columns (prep), so no per-thread scaling here.
#define KSTR 72
__global__ __launch_bounds__(512) void natten_attn_kernel(
    const __bf16* __restrict__ qkv, __bf16* __restrict__ o) {
  __shared__ __bf16 sK[196 * KSTR];
  __shared__ __bf16 sV[196 * KSTR];
  int tid = threadIdx.x;
  int bid = blockIdx.x;                 // 0..575
  int nB = bid / 288;
  int rem = bid - nB * 288;
  int head = rem / 36;
  int tile = rem - head * 36;
  int tr = tile / 6, tc = tile - tr * 6;
  int r0 = tr * 8, c0 = tc * 8;
  int loH = r0 - 3; loH = loH < 0 ? 0 : (loH > 41 ? 41 : loH);
  int loW = c0 - 3; loW = loW < 0 ? 0 : (loW > 41 ? 41 : loW);

  for (int j = tid; j < 196 * 8; j += 512) {
    int rowi = j >> 3, ch = j & 7;
    int rr = rowi / 14, cc = rowi - rr * 14;
    int hh = loH + rr; hh = hh > 47 ? 47 : hh;
    int wp = loW + cc; wp = wp > 47 ? 47 : wp;
    long base = (long)(nB * 2304 + hh * 48 + wp) * QKV_N + head * 64 + ch * 8;
    *(uint4*)&sK[rowi * KSTR + ch * 8] = *(const uint4*)&qkv[base + 512];
    *(uint4*)&sV[rowi * KSTR + ch * 8] = *(const uint4*)&qkv[base + 1024];
  }
  __syncthreads();

  int q = tid >> 3, s = tid & 7;        // 64 queries x 8 channel-slices
  int qr = q >> 3, qc = q & 7;
  int h = r0 + qr, w = c0 + qc;
  int pix = nB * 2304 + h * 48 + w;
  int hs = h - 3; hs = hs < 0 ? 0 : (hs > 41 ? 41 : hs); hs -= loH;
  int ws = w - 3; ws = ws < 0 ? 0 : (ws > 41 ? 41 : ws); ws -= loW;
  int base = (hs * 14 + ws) * KSTR + s * 8;

  // q fragment: 8 channels (scale already folded into weights)
  bf16x8 q0 = *(const bf16x8*)&qkv[(long)pix * QKV_N + head * 64 + s * 8];
  float qf[8];
#pragma unroll
  for (int t = 0; t < 8; ++t) qf[t] = (float)q0[t];

  // phase 1: 49 logits (8-ch partial + 8-lane shuffle reduce)
  float lg[49];
#pragma unroll
  for (int j = 0; j < 49; ++j) {
    int a = j / 7, b = j % 7;
    bf16x8 k0 = *(const bf16x8*)&sK[base + (a * 14 + b) * KSTR];
    float acc = 0.f;
#pragma unroll
    for (int t = 0; t < 8; ++t) acc = fmaf(qf[t], (float)k0[t], acc);
    acc += __shfl_xor(acc, 1);
    acc += __shfl_xor(acc, 2);
    acc += __shfl_xor(acc, 4);
    lg[j] = acc;
  }

  // softmax (replicated across the 8 lanes of a query)
  float mx = lg[0];
#pragma unroll
  for (int j = 1; j < 49; ++j) mx = fmaxf(mx, lg[j]);
  float sm = 0.f;
#pragma unroll
  for (int j = 0; j < 49; ++j) { lg[j] = __expf(lg[j] - mx); sm += lg[j]; }
  float inv = 1.f / sm;

  // phase 2: PV, 8 channels per lane
  float ov[8];
#pragma unroll
  for (int t = 0; t < 8; ++t) ov[t] = 0.f;
#pragma unroll
  for (int j = 0; j < 49; ++j) {
    int a = j / 7, b = j % 7;
    float pj = lg[j] * inv;
    bf16x8 v0 = *(const bf16x8*)&sV[base + (a * 14 + b) * KSTR];
#pragma unroll
    for (int t = 0; t < 8; ++t) ov[t] = fmaf(pj, (float)v0[t], ov[t]);
  }

  bf16x8 o0;
#pragma unroll
  for (int t = 0; t < 8; ++t) o0[t] = (__bf16)ov[t];
  *(bf16x8*)&o[(long)pix * D_MODEL + head * 64 + s * 8] = o0;
}

// ---------------- launch ----------------

extern "C" void kernel_launch(void* const* d_in, const int* in_sizes, int n_in,
                              void* d_out, int out_size, void* d_ws, size_t ws_size,
                              hipStream_t stream) {
  const float* x = (const float*)d_in[0];      // (2,48,48,512)
  const float* w_qkv = (const float*)d_in[1];  // (512,1536)
  const float* w_out = (const float*)d_in[2];  // (512,512)
  float* out = (float*)d_out;                  // (2,48,48,512)

  __bf16* ws = (__bf16*)d_ws;
  __bf16* xbf   = ws;                                   // 4608*512
  __bf16* wqkvT = xbf + N_PIX * D_MODEL;                // 1536*512
  __bf16* woutT = wqkvT + QKV_N * D_MODEL;              // 512*512
  __bf16* qkvb  = woutT + D_MODEL * D_MODEL;            // 4608*1536
  __bf16* obf   = qkvb + N_PIX * QKV_N;                 // 4608*512

  // prep: x->bf16 (2304 blocks) + w_qkv^T scaled (768) + w_out^T (256)
  prep_kernel<<<3328, 256, 0, stream>>>(x, w_qkv, w_out, xbf, wqkvT, woutT);
  // qkv = xbf @ w_qkv -> bf16 (4608 x 1536)
  gemm128_kernel<128><<<dim3(QKV_N / 128, N_PIX / 128), 256, 0, stream>>>(
      xbf, wqkvT, qkvb, N_PIX, QKV_N, D_MODEL, 0);
  // attention -> obf (4608 x 512)
  natten_attn_kernel<<<576, 512, 0, stream>>>(qkvb, obf);
  // out = obf @ w_out -> fp32
  gemm128_kernel<64><<<dim3(D_MODEL / 64, N_PIX / 128), 256, 0, stream>>>(
      obf, woutT, out, N_PIX, D_MODEL, D_MODEL, 1);
}

// Round 5
// 121.705 us; speedup vs baseline: 1.2583x; 1.0215x over previous
//
#include <hip/hip_runtime.h>
#include <hip/hip_bf16.h>

typedef __bf16 bf16x4 __attribute__((ext_vector_type(4)));
typedef __bf16 bf16x8 __attribute__((ext_vector_type(8)));
typedef float f32x4 __attribute__((ext_vector_type(4)));

#define N_PIX 4608      // 2*48*48
#define D_MODEL 512
#define QKV_N 1536

// async global->LDS, 16B per lane. LDS dest is wave-uniform base; HW adds lane*16.
__device__ __forceinline__ void gload_lds16(const void* g, void* l) {
  __builtin_amdgcn_global_load_lds(
      (const __attribute__((address_space(1))) unsigned int*)g,
      (__attribute__((address_space(3))) unsigned int*)l, 16, 0, 0);
}

// ---------------- fused prep: x->bf16 + both weight transposes ----------------
// blocks [0,2304): x convert; [2304,3072): w_qkv^T (q-scale folded); [3072,3328): w_out^T
__global__ __launch_bounds__(256) void prep_kernel(
    const float* __restrict__ x, const float* __restrict__ wq,
    const float* __restrict__ wo, __bf16* __restrict__ xbf,
    __bf16* __restrict__ wqT, __bf16* __restrict__ woT) {
  int b = blockIdx.x, tid = threadIdx.x;
  if (b < 2304) {
    int i = b * 1024 + tid * 4;
    float4 v = *(const float4*)&x[i];
    bf16x4 o = {(__bf16)v.x, (__bf16)v.y, (__bf16)v.z, (__bf16)v.w};
    *(bf16x4*)&xbf[i] = o;
    return;
  }
  __shared__ float tile[32][33];
  const float* src; __bf16* dst; int R, C, bx, by;
  bool is_wq;
  if (b < 3072) {
    int t = b - 2304; src = wq; dst = wqT; R = 512; C = 1536;
    bx = (t % 48) * 32; by = (t / 48) * 32; is_wq = true;
  } else {
    int t = b - 3072; src = wo; dst = woT; R = 512; C = 512;
    bx = (t & 15) * 32; by = (t >> 4) * 32; is_wq = false;
  }
  int tx = tid & 31, ty = tid >> 5;
#pragma unroll
  for (int i = 0; i < 32; i += 8)
    tile[ty + i][tx] = src[(by + ty + i) * C + bx + tx];
  __syncthreads();
#pragma unroll
  for (int i = 0; i < 32; i += 8) {
    int outrow = bx + ty + i;
    float v = tile[tx][ty + i];
    if (is_wq && outrow < 512) v *= 0.125f;  // fold q/sqrt(D_HEAD) into weights
    dst[outrow * R + by + tx] = (__bf16)v;
  }
}

// ---------------- bf16 MFMA GEMM, templated tile, dbuf global_load_lds --------
// C[MxN] = A[MxK] * Bt[NxK]^T. Block tile BM x BN, BK=32, 4 waves (2x2),
// wave tile (BM/2) x (BN/2). Grid-occupancy-first: small tiles -> more blocks/CU.
// Fragment layouts (verified m89): A[m=lane&15][k=quad*8+j]; Bt[n=lane&15][k=quad*8+j];
// C/D: row=quad*4+reg, col=lane&15.
template <int BM, int BN>
__global__ __launch_bounds__(256) void gemm_kernel(
    const __bf16* __restrict__ A, const __bf16* __restrict__ Bt,
    void* __restrict__ C, int M, int N, int K, int c_is_f32) {
  constexpr int MT = BM / 32;      // MFMA row-tiles per wave
  constexpr int NT = BN / 32;      // MFMA col-tiles per wave
  constexpr int AR = BM / 4;       // A rows staged per wave (16 or 32)
  constexpr int BR = BN / 4;       // B rows staged per wave (16 or 32)
  __shared__ __bf16 sA[2][BM * 32];
  __shared__ __bf16 sB[2][BN * 32];
  int tid = threadIdx.x;
  int wv = tid >> 6, lane = tid & 63;
  int quad = lane >> 4, r16 = lane & 15;
  int m0 = blockIdx.y * BM, n0 = blockIdx.x * BN;

  int rA = lane >> 2;           // 0..15
  int kc = (lane & 3) * 8;      // 0,8,16,24
  const __bf16* Ag0 = A + (long)(m0 + wv * AR + rA) * K + kc;
  const __bf16* Bg0 = Bt + (long)(n0 + wv * BR + rA) * K + kc;

  int mw = (wv & 1) * (BM / 2), nw = (wv >> 1) * (BN / 2);

  f32x4 acc[MT][NT];
#pragma unroll
  for (int mt = 0; mt < MT; ++mt)
#pragma unroll
    for (int nt = 0; nt < NT; ++nt) acc[mt][nt] = f32x4{0.f, 0.f, 0.f, 0.f};

  auto stage = [&](int buf, int k0) {
    gload_lds16(Ag0 + k0, &sA[buf][(wv * AR) * 32]);
    if (AR == 32)
      gload_lds16(Ag0 + (long)16 * K + k0, &sA[buf][(wv * AR + 16) * 32]);
    gload_lds16(Bg0 + k0, &sB[buf][(wv * BR) * 32]);
    if (BR == 32)
      gload_lds16(Bg0 + (long)16 * K + k0, &sB[buf][(wv * BR + 16) * 32]);
  };

  stage(0, 0);
  int cur = 0;
  for (int k0 = 0; k0 < K; k0 += 32) {
    __syncthreads();
    if (k0 + 32 < K) stage(cur ^ 1, k0 + 32);
    bf16x8 af[MT], bfr[NT];
#pragma unroll
    for (int mt = 0; mt < MT; ++mt)
      af[mt] = *(const bf16x8*)&sA[cur][(mw + mt * 16 + r16) * 32 + quad * 8];
#pragma unroll
    for (int nt = 0; nt < NT; ++nt)
      bfr[nt] = *(const bf16x8*)&sB[cur][(nw + nt * 16 + r16) * 32 + quad * 8];
#pragma unroll
    for (int mt = 0; mt < MT; ++mt)
#pragma unroll
      for (int nt = 0; nt < NT; ++nt)
        acc[mt][nt] = __builtin_amdgcn_mfma_f32_16x16x32_bf16(af[mt], bfr[nt], acc[mt][nt], 0, 0, 0);
    cur ^= 1;
  }

  __bf16* Cb = (__bf16*)C;
  float* Cf = (float*)C;
#pragma unroll
  for (int mt = 0; mt < MT; ++mt)
#pragma unroll
    for (int r = 0; r < 4; ++r) {
      int row = m0 + mw + mt * 16 + quad * 4 + r;
#pragma unroll
      for (int nt = 0; nt < NT; ++nt) {
        int col = n0 + nw + nt * 16 + r16;
        float v = acc[mt][nt][r];
        if (c_is_f32) Cf[(long)row * N + col] = v;
        else          Cb[(long)row * N + col] = (__bf16)v;
      }
    }
}

// ---------------- neighborhood attention, LDS-tiled, 512 threads ----------------
// Block = 8x8 query tile x 1 head, 8 waves. Stage 14x14 K/V halo (64ch bf16) in LDS.
// 8 lanes per query, each owns 8 channels. Row stride 72 elems (144 B).
// q-scale is pre-folded into w_qkv columns (prep).
#define KSTR 72
__global__ __launch_bounds__(512) void natten_attn_kernel(
    const __bf16* __restrict__ qkv, __bf16* __restrict__ o) {
  __shared__ __bf16 sK[196 * KSTR];
  __shared__ __bf16 sV[196 * KSTR];
  int tid = threadIdx.x;
  int bid = blockIdx.x;                 // 0..575
  int nB = bid / 288;
  int rem = bid - nB * 288;
  int head = rem / 36;
  int tile = rem - head * 36;
  int tr = tile / 6, tc = tile - tr * 6;
  int r0 = tr * 8, c0 = tc * 8;
  int loH = r0 - 3; loH = loH < 0 ? 0 : (loH > 41 ? 41 : loH);
  int loW = c0 - 3; loW = loW < 0 ? 0 : (loW > 41 ? 41 : loW);

  for (int j = tid; j < 196 * 8; j += 512) {
    int rowi = j >> 3, ch = j & 7;
    int rr = rowi / 14, cc = rowi - rr * 14;
    int hh = loH + rr; hh = hh > 47 ? 47 : hh;
    int wp = loW + cc; wp = wp > 47 ? 47 : wp;
    long base = (long)(nB * 2304 + hh * 48 + wp) * QKV_N + head * 64 + ch * 8;
    *(uint4*)&sK[rowi * KSTR + ch * 8] = *(const uint4*)&qkv[base + 512];
    *(uint4*)&sV[rowi * KSTR + ch * 8] = *(const uint4*)&qkv[base + 1024];
  }
  __syncthreads();

  int q = tid >> 3, s = tid & 7;        // 64 queries x 8 channel-slices
  int qr = q >> 3, qc = q & 7;
  int h = r0 + qr, w = c0 + qc;
  int pix = nB * 2304 + h * 48 + w;
  int hs = h - 3; hs = hs < 0 ? 0 : (hs > 41 ? 41 : hs); hs -= loH;
  int ws = w - 3; ws = ws < 0 ? 0 : (ws > 41 ? 41 : ws); ws -= loW;
  int base = (hs * 14 + ws) * KSTR + s * 8;

  bf16x8 q0 = *(const bf16x8*)&qkv[(long)pix * QKV_N + head * 64 + s * 8];
  float qf[8];
#pragma unroll
  for (int t = 0; t < 8; ++t) qf[t] = (float)q0[t];

  float lg[49];
#pragma unroll
  for (int j = 0; j < 49; ++j) {
    int a = j / 7, b = j % 7;
    bf16x8 k0 = *(const bf16x8*)&sK[base + (a * 14 + b) * KSTR];
    float acc = 0.f;
#pragma unroll
    for (int t = 0; t < 8; ++t) acc = fmaf(qf[t], (float)k0[t], acc);
    acc += __shfl_xor(acc, 1);
    acc += __shfl_xor(acc, 2);
    acc += __shfl_xor(acc, 4);
    lg[j] = acc;
  }

  float mx = lg[0];
#pragma unroll
  for (int j = 1; j < 49; ++j) mx = fmaxf(mx, lg[j]);
  float sm = 0.f;
#pragma unroll
  for (int j = 0; j < 49; ++j) { lg[j] = __expf(lg[j] - mx); sm += lg[j]; }
  float inv = 1.f / sm;

  float ov[8];
#pragma unroll
  for (int t = 0; t < 8; ++t) ov[t] = 0.f;
#pragma unroll
  for (int j = 0; j < 49; ++j) {
    int a = j / 7, b = j % 7;
    float pj = lg[j] * inv;
    bf16x8 v0 = *(const bf16x8*)&sV[base + (a * 14 + b) * KSTR];
#pragma unroll
    for (int t = 0; t < 8; ++t) ov[t] = fmaf(pj, (float)v0[t], ov[t]);
  }

  bf16x8 o0;
#pragma unroll
  for (int t = 0; t < 8; ++t) o0[t] = (__bf16)ov[t];
  *(bf16x8*)&o[(long)pix * D_MODEL + head * 64 + s * 8] = o0;
}

// ---------------- launch ----------------

extern "C" void kernel_launch(void* const* d_in, const int* in_sizes, int n_in,
                              void* d_out, int out_size, void* d_ws, size_t ws_size,
                              hipStream_t stream) {
  const float* x = (const float*)d_in[0];      // (2,48,48,512)
  const float* w_qkv = (const float*)d_in[1];  // (512,1536)
  const float* w_out = (const float*)d_in[2];  // (512,512)
  float* out = (float*)d_out;                  // (2,48,48,512)

  __bf16* ws = (__bf16*)d_ws;
  __bf16* xbf   = ws;                                   // 4608*512
  __bf16* wqkvT = xbf + N_PIX * D_MODEL;                // 1536*512
  __bf16* woutT = wqkvT + QKV_N * D_MODEL;              // 512*512
  __bf16* qkvb  = woutT + D_MODEL * D_MODEL;            // 4608*1536
  __bf16* obf   = qkvb + N_PIX * QKV_N;                 // 4608*512

  // prep: x->bf16 (2304 blocks) + w_qkv^T scaled (768) + w_out^T (256)
  prep_kernel<<<3328, 256, 0, stream>>>(x, w_qkv, w_out, xbf, wqkvT, woutT);
  // qkv = xbf @ w_qkv -> bf16 (4608 x 1536); 64x128 tile -> 72x12=864 blocks (3.4/CU)
  gemm_kernel<64, 128><<<dim3(QKV_N / 128, N_PIX / 64), 256, 0, stream>>>(
      xbf, wqkvT, qkvb, N_PIX, QKV_N, D_MODEL, 0);
  // attention -> obf (4608 x 512)
  natten_attn_kernel<<<576, 512, 0, stream>>>(qkvb, obf);
  // out = obf @ w_out -> fp32; 64x64 tile -> 72x8=576 blocks (2.25/CU)
  gemm_kernel<64, 64><<<dim3(D_MODEL / 64, N_PIX / 64), 256, 0, stream>>>(
      obf, woutT, out, N_PIX, D_MODEL, D_MODEL, 1);
}